// Round 2
// baseline (193.747 us; speedup 1.0000x reference)
//
#include <hip/hip_runtime.h>
#include <math.h>

#define NL 8
#define NH 2048
#define NO 1000

__device__ __forceinline__ float dot4(float4 a, float4 b) {
    return a.x * b.x + a.y * b.y + a.z * b.z + a.w * b.w;
}

__device__ __forceinline__ float4 relu4(float4 a) {
    return make_float4(fmaxf(a.x, 0.f), fmaxf(a.y, 0.f), fmaxf(a.z, 0.f), fmaxf(a.w, 0.f));
}

__device__ __forceinline__ float wave_sum(float v) {
#pragma unroll
    for (int off = 32; off > 0; off >>= 1) v += __shfl_xor(v, off);
    return v;
}

// Kernel A: fused 6-GEMV + gate combine. One wave per (layer, row).
// 2-deep software pipeline with distinct registers per gate so ~8 loads
// stay in flight per wave (R1 was vmcnt-serialized at 48 VGPR).
__global__ __launch_bounds__(256, 4) void gru_gates_kernel(
    const float* __restrict__ x,    // [NH]
    const float* __restrict__ h,    // [NL, NH]
    const float* __restrict__ W_ir, const float* __restrict__ b_ir,
    const float* __restrict__ W_hr, const float* __restrict__ b_hr,
    const float* __restrict__ W_h1, const float* __restrict__ b_h1,
    const float* __restrict__ W_x1, const float* __restrict__ b_x1,
    const float* __restrict__ W_iu, const float* __restrict__ b_iu,
    const float* __restrict__ W_hu, const float* __restrict__ b_hu,
    float* __restrict__ new_h)      // [NL, NH]  (== d_out + NO)
{
    const int wave = (blockIdx.x * blockDim.x + threadIdx.x) >> 6;
    const int lane = threadIdx.x & 63;
    const int l   = wave >> 11;     // / NH
    const int row = wave & (NH - 1);

    // inp[0] = x, inp[l>0] = h[l-1]   (B == 1)
    const float4* __restrict__ vi = (const float4*)((l == 0) ? x : (h + (size_t)(l - 1) * NH));
    const float4* __restrict__ vh = (const float4*)(h + (size_t)l * NH);

    const size_t wbase = ((size_t)l * NH + row) * NH;
    const float4* __restrict__ wir = (const float4*)(W_ir + wbase);
    const float4* __restrict__ whr = (const float4*)(W_hr + wbase);
    const float4* __restrict__ wh1 = (const float4*)(W_h1 + wbase);
    const float4* __restrict__ wx1 = (const float4*)(W_x1 + wbase);
    const float4* __restrict__ wiu = (const float4*)(W_iu + wbase);
    const float4* __restrict__ whu = (const float4*)(W_hu + wbase);

    float s_ir = 0.f, s_hr = 0.f, s_h1 = 0.f, s_x1 = 0.f, s_iu = 0.f, s_hu = 0.f;

    // ---- prologue: issue chunk 0's loads ----
    int k = lane;
    float4 a0   = vi[k];
    float4 b0   = vh[k];
    float4 t_ir = wir[k];
    float4 t_hr = whr[k];
    float4 t_h1 = wh1[k];
    float4 t_x1 = wx1[k];
    float4 t_iu = wiu[k];
    float4 t_hu = whu[k];

#pragma unroll
    for (int it = 0; it < NH / 4 / 64 - 1; ++it) {   // 7 pipelined iterations
        const int kn = (it + 1) * 64 + lane;
        // issue next chunk's loads (independent registers -> stay in flight)
        float4 a1   = vi[kn];
        float4 b1   = vh[kn];
        float4 n_ir = wir[kn];
        float4 n_hr = whr[kn];
        float4 n_h1 = wh1[kn];
        float4 n_x1 = wx1[kn];
        float4 n_iu = wiu[kn];
        float4 n_hu = whu[kn];
        // consume current chunk
        s_ir += dot4(a0, t_ir);
        s_hr += dot4(b0, t_hr);
        s_h1 += dot4(b0, t_h1);
        s_x1 += dot4(a0, t_x1);
        s_iu += dot4(a0, t_iu);
        s_hu += dot4(b0, t_hu);
        // rotate
        a0 = a1; b0 = b1;
        t_ir = n_ir; t_hr = n_hr; t_h1 = n_h1;
        t_x1 = n_x1; t_iu = n_iu; t_hu = n_hu;
    }
    // epilogue chunk
    s_ir += dot4(a0, t_ir);
    s_hr += dot4(b0, t_hr);
    s_h1 += dot4(b0, t_h1);
    s_x1 += dot4(a0, t_x1);
    s_iu += dot4(a0, t_iu);
    s_hu += dot4(b0, t_hu);

    s_ir = wave_sum(s_ir);
    s_hr = wave_sum(s_hr);
    s_h1 = wave_sum(s_h1);
    s_x1 = wave_sum(s_x1);
    s_iu = wave_sum(s_iu);
    s_hu = wave_sum(s_hu);

    if (lane == 0) {
        const int bi = l * NH + row;
        const float dir = s_ir + b_ir[bi];
        const float dhr = s_hr + b_hr[bi];
        const float dh1 = s_h1 + b_h1[bi];
        const float dx1 = s_x1 + b_x1[bi];
        const float diu = s_iu + b_iu[bi];
        const float dhu = s_hu + b_hu[bi];
        const float reset = 1.f / (1.f + expf(-(dir + dhr)));
        const float r     = tanhf(reset * dh1 + dx1);
        const float u     = 1.f / (1.f + expf(-(diu + dhu)));
        const float hv    = h[bi];
        new_h[bi] = (1.f - u) * r + u * hv;
    }
}

// Kernel B: FC GEMV on relu(new_h[last]). One wave per output row, 2-deep pipeline.
__global__ __launch_bounds__(256) void fc_kernel(
    const float* __restrict__ new_h,  // [NL, NH]
    const float* __restrict__ W_fc,   // [NO, NH]
    const float* __restrict__ b_fc,   // [NO]
    float* __restrict__ logits)       // [NO] (workspace)
{
    const int wave = (blockIdx.x * blockDim.x + threadIdx.x) >> 6;
    const int lane = threadIdx.x & 63;
    if (wave >= NO) return;
    const float4* __restrict__ v = (const float4*)(new_h + (size_t)(NL - 1) * NH);
    const float4* __restrict__ w = (const float4*)(W_fc + (size_t)wave * NH);
    float s = 0.f;
    float4 v0 = v[lane];
    float4 w0 = w[lane];
#pragma unroll
    for (int it = 0; it < NH / 4 / 64 - 1; ++it) {
        const int kn = (it + 1) * 64 + lane;
        float4 v1 = v[kn];
        float4 w1 = w[kn];
        s += dot4(relu4(v0), w0);
        v0 = v1; w0 = w1;
    }
    s += dot4(relu4(v0), w0);
    s = wave_sum(s);
    if (lane == 0) logits[wave] = s + b_fc[wave];
}

// Kernel C: log_softmax over NO=1000 elements, single block of 1024.
__global__ __launch_bounds__(1024) void lsm_kernel(
    const float* __restrict__ logits, float* __restrict__ out)
{
    const int t = threadIdx.x;
    const int lane = t & 63;
    const int wid = t >> 6;
    __shared__ float sred[16];

    const float v = (t < NO) ? logits[t] : -INFINITY;

    // block max
    float m = v;
#pragma unroll
    for (int off = 32; off > 0; off >>= 1) m = fmaxf(m, __shfl_xor(m, off));
    if (lane == 0) sred[wid] = m;
    __syncthreads();
    if (wid == 0) {
        float mm = (t < 16) ? sred[t] : -INFINITY;
#pragma unroll
        for (int off = 8; off > 0; off >>= 1) mm = fmaxf(mm, __shfl_xor(mm, off));
        if (t == 0) sred[0] = mm;
    }
    __syncthreads();
    const float M = sred[0];
    __syncthreads();

    // block sum of exp
    float e = (t < NO) ? expf(v - M) : 0.f;
    float s = e;
#pragma unroll
    for (int off = 32; off > 0; off >>= 1) s += __shfl_xor(s, off);
    if (lane == 0) sred[wid] = s;
    __syncthreads();
    if (wid == 0) {
        float ss = (t < 16) ? sred[t] : 0.f;
#pragma unroll
        for (int off = 8; off > 0; off >>= 1) ss += __shfl_xor(ss, off);
        if (t == 0) sred[0] = ss;
    }
    __syncthreads();
    const float lse = M + logf(sred[0]);

    if (t < NO) out[t] = v - lse;
}

extern "C" void kernel_launch(void* const* d_in, const int* in_sizes, int n_in,
                              void* d_out, int out_size, void* d_ws, size_t ws_size,
                              hipStream_t stream) {
    const float* x    = (const float*)d_in[0];
    const float* h    = (const float*)d_in[1];
    const float* W_ir = (const float*)d_in[2];
    const float* b_ir = (const float*)d_in[3];
    const float* W_hr = (const float*)d_in[4];
    const float* b_hr = (const float*)d_in[5];
    const float* W_h1 = (const float*)d_in[6];
    const float* b_h1 = (const float*)d_in[7];
    const float* W_x1 = (const float*)d_in[8];
    const float* b_x1 = (const float*)d_in[9];
    const float* W_iu = (const float*)d_in[10];
    const float* b_iu = (const float*)d_in[11];
    const float* W_hu = (const float*)d_in[12];
    const float* b_hu = (const float*)d_in[13];
    const float* W_fc = (const float*)d_in[14];
    const float* b_fc = (const float*)d_in[15];

    float* out    = (float*)d_out;      // [NO] log-softmax output
    float* new_h  = out + NO;           // [NL*NH] second tuple element
    float* logits = (float*)d_ws;       // [NO] scratch

    // Kernel A: NL*NH waves, 4 waves per 256-thread block.
    gru_gates_kernel<<<(NL * NH) / 4, 256, 0, stream>>>(
        x, h, W_ir, b_ir, W_hr, b_hr, W_h1, b_h1, W_x1, b_x1,
        W_iu, b_iu, W_hu, b_hu, new_h);

    // Kernel B: NO waves, 4 waves per block -> 250 blocks.
    fc_kernel<<<(NO + 3) / 4, 256, 0, stream>>>(new_h, W_fc, b_fc, logits);

    // Kernel C: single block log-softmax.
    lsm_kernel<<<1, 1024, 0, stream>>>(logits, out);
}

// Round 3
// 142.885 us; speedup vs baseline: 1.3560x; 1.3560x over previous
//
#include <hip/hip_runtime.h>
#include <math.h>

#define NL 8
#define NH 2048
#define NO 1000

__device__ __forceinline__ float dot4(float4 a, float4 b) {
    return a.x * b.x + a.y * b.y + a.z * b.z + a.w * b.w;
}

__device__ __forceinline__ float4 relu4(float4 a) {
    return make_float4(fmaxf(a.x, 0.f), fmaxf(a.y, 0.f), fmaxf(a.z, 0.f), fmaxf(a.w, 0.f));
}

__device__ __forceinline__ float wave_sum(float v) {
#pragma unroll
    for (int off = 32; off > 0; off >>= 1) v += __shfl_xor(v, off);
    return v;
}

// Kernel A: fused 6-GEMV + gate combine. One wave per (layer, row).
// Unroll-by-2 with two independent register sets (issue 16 loads, then
// consume 16) to double memory-level parallelism vs R1's 48-VGPR loop.
// NO launch_bounds min-waves spec: R2 showed it caps VGPR at 64 -> spills.
__global__ __launch_bounds__(256) void gru_gates_kernel(
    const float* __restrict__ x,    // [NH]
    const float* __restrict__ h,    // [NL, NH]
    const float* __restrict__ W_ir, const float* __restrict__ b_ir,
    const float* __restrict__ W_hr, const float* __restrict__ b_hr,
    const float* __restrict__ W_h1, const float* __restrict__ b_h1,
    const float* __restrict__ W_x1, const float* __restrict__ b_x1,
    const float* __restrict__ W_iu, const float* __restrict__ b_iu,
    const float* __restrict__ W_hu, const float* __restrict__ b_hu,
    float* __restrict__ new_h)      // [NL, NH]  (== d_out + NO)
{
    const int wave = (blockIdx.x * blockDim.x + threadIdx.x) >> 6;
    const int lane = threadIdx.x & 63;
    const int l   = wave >> 11;     // / NH
    const int row = wave & (NH - 1);

    // inp[0] = x, inp[l>0] = h[l-1]   (B == 1)
    const float4* __restrict__ vi = (const float4*)((l == 0) ? x : (h + (size_t)(l - 1) * NH));
    const float4* __restrict__ vh = (const float4*)(h + (size_t)l * NH);

    const size_t wbase = ((size_t)l * NH + row) * NH;
    const float4* __restrict__ wir = (const float4*)(W_ir + wbase);
    const float4* __restrict__ whr = (const float4*)(W_hr + wbase);
    const float4* __restrict__ wh1 = (const float4*)(W_h1 + wbase);
    const float4* __restrict__ wx1 = (const float4*)(W_x1 + wbase);
    const float4* __restrict__ wiu = (const float4*)(W_iu + wbase);
    const float4* __restrict__ whu = (const float4*)(W_hu + wbase);

    float s_ir = 0.f, s_hr = 0.f, s_h1 = 0.f, s_x1 = 0.f, s_iu = 0.f, s_hu = 0.f;

#pragma unroll
    for (int it = 0; it < NH / 4 / 64 / 2; ++it) {   // 4 iterations, 2 chunks each
        const int k0 = it * 128 + lane;
        const int k1 = k0 + 64;
        // ---- issue ALL 16 loads (two independent register sets) ----
        const float4 a0   = vi[k0];
        const float4 b0   = vh[k0];
        const float4 t0_ir = wir[k0];
        const float4 t0_hr = whr[k0];
        const float4 t0_h1 = wh1[k0];
        const float4 t0_x1 = wx1[k0];
        const float4 t0_iu = wiu[k0];
        const float4 t0_hu = whu[k0];
        const float4 a1   = vi[k1];
        const float4 b1   = vh[k1];
        const float4 t1_ir = wir[k1];
        const float4 t1_hr = whr[k1];
        const float4 t1_h1 = wh1[k1];
        const float4 t1_x1 = wx1[k1];
        const float4 t1_iu = wiu[k1];
        const float4 t1_hu = whu[k1];
        // ---- consume both ----
        s_ir += dot4(a0, t0_ir) + dot4(a1, t1_ir);
        s_hr += dot4(b0, t0_hr) + dot4(b1, t1_hr);
        s_h1 += dot4(b0, t0_h1) + dot4(b1, t1_h1);
        s_x1 += dot4(a0, t0_x1) + dot4(a1, t1_x1);
        s_iu += dot4(a0, t0_iu) + dot4(a1, t1_iu);
        s_hu += dot4(b0, t0_hu) + dot4(b1, t1_hu);
    }

    s_ir = wave_sum(s_ir);
    s_hr = wave_sum(s_hr);
    s_h1 = wave_sum(s_h1);
    s_x1 = wave_sum(s_x1);
    s_iu = wave_sum(s_iu);
    s_hu = wave_sum(s_hu);

    if (lane == 0) {
        const int bi = l * NH + row;
        const float dir = s_ir + b_ir[bi];
        const float dhr = s_hr + b_hr[bi];
        const float dh1 = s_h1 + b_h1[bi];
        const float dx1 = s_x1 + b_x1[bi];
        const float diu = s_iu + b_iu[bi];
        const float dhu = s_hu + b_hu[bi];
        const float reset = 1.f / (1.f + expf(-(dir + dhr)));
        const float r     = tanhf(reset * dh1 + dx1);
        const float u     = 1.f / (1.f + expf(-(diu + dhu)));
        const float hv    = h[bi];
        new_h[bi] = (1.f - u) * r + u * hv;
    }
}

// Kernel B: FC GEMV on relu(new_h[last]). One wave per output row.
__global__ __launch_bounds__(256) void fc_kernel(
    const float* __restrict__ new_h,  // [NL, NH]
    const float* __restrict__ W_fc,   // [NO, NH]
    const float* __restrict__ b_fc,   // [NO]
    float* __restrict__ logits)       // [NO] (workspace)
{
    const int wave = (blockIdx.x * blockDim.x + threadIdx.x) >> 6;
    const int lane = threadIdx.x & 63;
    if (wave >= NO) return;
    const float4* __restrict__ v = (const float4*)(new_h + (size_t)(NL - 1) * NH);
    const float4* __restrict__ w = (const float4*)(W_fc + (size_t)wave * NH);
    float s = 0.f;
#pragma unroll
    for (int it = 0; it < NH / 4 / 64 / 2; ++it) {
        const int k0 = it * 128 + lane;
        const int k1 = k0 + 64;
        const float4 v0 = v[k0];
        const float4 w0 = w[k0];
        const float4 v1 = v[k1];
        const float4 w1 = w[k1];
        s += dot4(relu4(v0), w0) + dot4(relu4(v1), w1);
    }
    s = wave_sum(s);
    if (lane == 0) logits[wave] = s + b_fc[wave];
}

// Kernel C: log_softmax over NO=1000 elements, single block of 1024.
__global__ __launch_bounds__(1024) void lsm_kernel(
    const float* __restrict__ logits, float* __restrict__ out)
{
    const int t = threadIdx.x;
    const int lane = t & 63;
    const int wid = t >> 6;
    __shared__ float sred[16];

    const float v = (t < NO) ? logits[t] : -INFINITY;

    // block max
    float m = v;
#pragma unroll
    for (int off = 32; off > 0; off >>= 1) m = fmaxf(m, __shfl_xor(m, off));
    if (lane == 0) sred[wid] = m;
    __syncthreads();
    if (wid == 0) {
        float mm = (t < 16) ? sred[t] : -INFINITY;
#pragma unroll
        for (int off = 8; off > 0; off >>= 1) mm = fmaxf(mm, __shfl_xor(mm, off));
        if (t == 0) sred[0] = mm;
    }
    __syncthreads();
    const float M = sred[0];
    __syncthreads();

    // block sum of exp
    float e = (t < NO) ? expf(v - M) : 0.f;
    float s = e;
#pragma unroll
    for (int off = 32; off > 0; off >>= 1) s += __shfl_xor(s, off);
    if (lane == 0) sred[wid] = s;
    __syncthreads();
    if (wid == 0) {
        float ss = (t < 16) ? sred[t] : 0.f;
#pragma unroll
        for (int off = 8; off > 0; off >>= 1) ss += __shfl_xor(ss, off);
        if (t == 0) sred[0] = ss;
    }
    __syncthreads();
    const float lse = M + logf(sred[0]);

    if (t < NO) out[t] = v - lse;
}

extern "C" void kernel_launch(void* const* d_in, const int* in_sizes, int n_in,
                              void* d_out, int out_size, void* d_ws, size_t ws_size,
                              hipStream_t stream) {
    const float* x    = (const float*)d_in[0];
    const float* h    = (const float*)d_in[1];
    const float* W_ir = (const float*)d_in[2];
    const float* b_ir = (const float*)d_in[3];
    const float* W_hr = (const float*)d_in[4];
    const float* b_hr = (const float*)d_in[5];
    const float* W_h1 = (const float*)d_in[6];
    const float* b_h1 = (const float*)d_in[7];
    const float* W_x1 = (const float*)d_in[8];
    const float* b_x1 = (const float*)d_in[9];
    const float* W_iu = (const float*)d_in[10];
    const float* b_iu = (const float*)d_in[11];
    const float* W_hu = (const float*)d_in[12];
    const float* b_hu = (const float*)d_in[13];
    const float* W_fc = (const float*)d_in[14];
    const float* b_fc = (const float*)d_in[15];

    float* out    = (float*)d_out;      // [NO] log-softmax output
    float* new_h  = out + NO;           // [NL*NH] second tuple element
    float* logits = (float*)d_ws;       // [NO] scratch

    // Kernel A: NL*NH waves, 4 waves per 256-thread block.
    gru_gates_kernel<<<(NL * NH) / 4, 256, 0, stream>>>(
        x, h, W_ir, b_ir, W_hr, b_hr, W_h1, b_h1, W_x1, b_x1,
        W_iu, b_iu, W_hu, b_hu, new_h);

    // Kernel B: NO waves, 4 waves per block -> 250 blocks.
    fc_kernel<<<(NO + 3) / 4, 256, 0, stream>>>(new_h, W_fc, b_fc, logits);

    // Kernel C: single block log-softmax.
    lsm_kernel<<<1, 1024, 0, stream>>>(logits, out);
}

// Round 4
// 142.047 us; speedup vs baseline: 1.3640x; 1.0059x over previous
//
#include <hip/hip_runtime.h>
#include <math.h>

#define NL 8
#define NH 2048
#define NO 1000

__device__ __forceinline__ float dot4(float4 a, float4 b) {
    return a.x * b.x + a.y * b.y + a.z * b.z + a.w * b.w;
}

__device__ __forceinline__ float4 relu4(float4 a) {
    return make_float4(fmaxf(a.x, 0.f), fmaxf(a.y, 0.f), fmaxf(a.z, 0.f), fmaxf(a.w, 0.f));
}

__device__ __forceinline__ float wave_sum(float v) {
#pragma unroll
    for (int off = 32; off > 0; off >>= 1) v += __shfl_xor(v, off);
    return v;
}

// Kernel A: one block (384 thr = 6 waves) per (layer,row); one wave per gate.
// Each wave streams ONE 8KB weight row via 8 independent float4 loads ->
// ~8KB in flight per wave, ~3x the per-CU MLP of the 6-streams-per-wave form.
__global__ __launch_bounds__(384) void gru_gates_kernel(
    const float* __restrict__ x,    // [NH]
    const float* __restrict__ h,    // [NL, NH]
    const float* __restrict__ W_ir, const float* __restrict__ b_ir,
    const float* __restrict__ W_hr, const float* __restrict__ b_hr,
    const float* __restrict__ W_h1, const float* __restrict__ b_h1,
    const float* __restrict__ W_x1, const float* __restrict__ b_x1,
    const float* __restrict__ W_iu, const float* __restrict__ b_iu,
    const float* __restrict__ W_hu, const float* __restrict__ b_hu,
    float* __restrict__ new_h)      // [NL, NH]  (== d_out + NO)
{
    const int bi   = blockIdx.x;          // 0 .. NL*NH-1  == l*NH + row
    const int l    = bi >> 11;            // / NH
    const int g    = threadIdx.x >> 6;    // gate id 0..5 (wave-uniform)
    const int lane = threadIdx.x & 63;

    __shared__ float part[6];

    // gate -> (weight matrix, bias, input vector)
    // 0:ir(vi) 1:hr(vh) 2:h1(vh) 3:x1(vi) 4:iu(vi) 5:hu(vh)
    const float* __restrict__ W;
    const float* __restrict__ bv;
    const float* vecf;
    const float* vi = (l == 0) ? x : (h + (size_t)(l - 1) * NH);
    const float* vh = h + (size_t)l * NH;
    switch (g) {
        case 0:  W = W_ir; bv = b_ir; vecf = vi; break;
        case 1:  W = W_hr; bv = b_hr; vecf = vh; break;
        case 2:  W = W_h1; bv = b_h1; vecf = vh; break;
        case 3:  W = W_x1; bv = b_x1; vecf = vi; break;
        case 4:  W = W_iu; bv = b_iu; vecf = vi; break;
        default: W = W_hu; bv = b_hu; vecf = vh; break;
    }
    const float4* __restrict__ wrow = (const float4*)(W + (size_t)bi * NH);
    const float4* __restrict__ vec  = (const float4*)vecf;

    // Issue all 8 weight loads first (independent regs -> deep in flight);
    // vector chunks are L1/L2-hot and interleave with the dots.
    const float4 w0 = wrow[lane +   0];
    const float4 w1 = wrow[lane +  64];
    const float4 w2 = wrow[lane + 128];
    const float4 w3 = wrow[lane + 192];
    const float4 w4 = wrow[lane + 256];
    const float4 w5 = wrow[lane + 320];
    const float4 w6 = wrow[lane + 384];
    const float4 w7 = wrow[lane + 448];

    float s;
    s  = dot4(vec[lane +   0], w0);
    s += dot4(vec[lane +  64], w1);
    s += dot4(vec[lane + 128], w2);
    s += dot4(vec[lane + 192], w3);
    s += dot4(vec[lane + 256], w4);
    s += dot4(vec[lane + 320], w5);
    s += dot4(vec[lane + 384], w6);
    s += dot4(vec[lane + 448], w7);

    s = wave_sum(s);
    if (lane == 0) part[g] = s + bv[bi];
    __syncthreads();

    if (threadIdx.x == 0) {
        const float reset = 1.f / (1.f + expf(-(part[0] + part[1])));
        const float r     = tanhf(reset * part[2] + part[3]);
        const float u     = 1.f / (1.f + expf(-(part[4] + part[5])));
        const float hv    = h[bi];
        new_h[bi] = (1.f - u) * r + u * hv;
    }
}

// Kernel B: FC GEMV on relu(new_h[last]). One wave per output row.
__global__ __launch_bounds__(256) void fc_kernel(
    const float* __restrict__ new_h,  // [NL, NH]
    const float* __restrict__ W_fc,   // [NO, NH]
    const float* __restrict__ b_fc,   // [NO]
    float* __restrict__ logits)       // [NO] (workspace)
{
    const int wave = (blockIdx.x * blockDim.x + threadIdx.x) >> 6;
    const int lane = threadIdx.x & 63;
    if (wave >= NO) return;
    const float4* __restrict__ v = (const float4*)(new_h + (size_t)(NL - 1) * NH);
    const float4* __restrict__ w = (const float4*)(W_fc + (size_t)wave * NH);
    float s = 0.f;
#pragma unroll
    for (int it = 0; it < NH / 4 / 64 / 2; ++it) {
        const int k0 = it * 128 + lane;
        const int k1 = k0 + 64;
        const float4 v0 = v[k0];
        const float4 w0 = w[k0];
        const float4 v1 = v[k1];
        const float4 w1 = w[k1];
        s += dot4(relu4(v0), w0) + dot4(relu4(v1), w1);
    }
    s = wave_sum(s);
    if (lane == 0) logits[wave] = s + b_fc[wave];
}

// Kernel C: log_softmax over NO=1000 elements, single block of 1024.
__global__ __launch_bounds__(1024) void lsm_kernel(
    const float* __restrict__ logits, float* __restrict__ out)
{
    const int t = threadIdx.x;
    const int lane = t & 63;
    const int wid = t >> 6;
    __shared__ float sred[16];

    const float v = (t < NO) ? logits[t] : -INFINITY;

    // block max
    float m = v;
#pragma unroll
    for (int off = 32; off > 0; off >>= 1) m = fmaxf(m, __shfl_xor(m, off));
    if (lane == 0) sred[wid] = m;
    __syncthreads();
    if (wid == 0) {
        float mm = (t < 16) ? sred[t] : -INFINITY;
#pragma unroll
        for (int off = 8; off > 0; off >>= 1) mm = fmaxf(mm, __shfl_xor(mm, off));
        if (t == 0) sred[0] = mm;
    }
    __syncthreads();
    const float M = sred[0];
    __syncthreads();

    // block sum of exp
    float e = (t < NO) ? expf(v - M) : 0.f;
    float s = e;
#pragma unroll
    for (int off = 32; off > 0; off >>= 1) s += __shfl_xor(s, off);
    if (lane == 0) sred[wid] = s;
    __syncthreads();
    if (wid == 0) {
        float ss = (t < 16) ? sred[t] : 0.f;
#pragma unroll
        for (int off = 8; off > 0; off >>= 1) ss += __shfl_xor(ss, off);
        if (t == 0) sred[0] = ss;
    }
    __syncthreads();
    const float lse = M + logf(sred[0]);

    if (t < NO) out[t] = v - lse;
}

extern "C" void kernel_launch(void* const* d_in, const int* in_sizes, int n_in,
                              void* d_out, int out_size, void* d_ws, size_t ws_size,
                              hipStream_t stream) {
    const float* x    = (const float*)d_in[0];
    const float* h    = (const float*)d_in[1];
    const float* W_ir = (const float*)d_in[2];
    const float* b_ir = (const float*)d_in[3];
    const float* W_hr = (const float*)d_in[4];
    const float* b_hr = (const float*)d_in[5];
    const float* W_h1 = (const float*)d_in[6];
    const float* b_h1 = (const float*)d_in[7];
    const float* W_x1 = (const float*)d_in[8];
    const float* b_x1 = (const float*)d_in[9];
    const float* W_iu = (const float*)d_in[10];
    const float* b_iu = (const float*)d_in[11];
    const float* W_hu = (const float*)d_in[12];
    const float* b_hu = (const float*)d_in[13];
    const float* W_fc = (const float*)d_in[14];
    const float* b_fc = (const float*)d_in[15];

    float* out    = (float*)d_out;      // [NO] log-softmax output
    float* new_h  = out + NO;           // [NL*NH] second tuple element
    float* logits = (float*)d_ws;       // [NO] scratch

    // Kernel A: one block per (layer,row); 6 waves = 6 gates.
    gru_gates_kernel<<<NL * NH, 384, 0, stream>>>(
        x, h, W_ir, b_ir, W_hr, b_hr, W_h1, b_h1, W_x1, b_x1,
        W_iu, b_iu, W_hu, b_hu, new_h);

    // Kernel B: NO waves, 4 waves per block -> 250 blocks.
    fc_kernel<<<(NO + 3) / 4, 256, 0, stream>>>(new_h, W_fc, b_fc, logits);

    // Kernel C: single block log-softmax.
    lsm_kernel<<<1, 1024, 0, stream>>>(logits, out);
}